// Round 4
// baseline (970.429 us; speedup 1.0000x reference)
//
#include <hip/hip_runtime.h>

#define NB 2
#define D 32
#define H 128
#define NSTEPS 8
#define BT 256
#define TN 512   // tanh LUT entries over prescaled v in [-14, 14]

typedef _Float16 f16;
typedef _Float16 f16x2 __attribute__((ext_vector_type(2)));
typedef _Float16 f16x8 __attribute__((ext_vector_type(8)));
typedef float    f32x4 __attribute__((ext_vector_type(4)));
typedef unsigned int uint;

// Weights/biases feeding a tanh are pre-scaled by 2*log2(e) at staging time, so
// the MFMA accumulator is already v = 2*log2e*z:  tanh(z) = 1 - 2/(1+2^v).
#define TSCL 2.8853900817779268f

__device__ __forceinline__ uint pku(float a, float b) {
    return __builtin_bit_cast(uint, __builtin_amdgcn_cvt_pkrtz(a, b));
}
__device__ __forceinline__ float lo32(uint u) { return (float)__builtin_bit_cast(f16x2, u)[0]; }
__device__ __forceinline__ float hi32(uint u) { return (float)__builtin_bit_cast(f16x2, u)[1]; }

__device__ const float CC[6] = {0.f, 0.2f, 0.3f, 0.8f, 8.f/9.f, 1.f};

// LDS: W1/W2 weights (fragment-ordered, k-permuted) + tanh LUT. ~46.7 KB.
//
// BOTTLENECK MODEL (R0..R13 measured): occupancy engineering (27%..40%, both
// directions) never moved dur (747..862). Kernel is VALU-ISSUE bound:
// ~2700 VALU cyc/wave/stage, of which ~2300 = 128 transcendental ops
// (64 tanh x {exp2, rcp}, ~16 cyc/wave64 each). MFMA only ~233 cyc/stage.
// => This round replaces tanh's 2 trans ops with an LDS lookup (7 full-rate
// VALU ops + 2 ds_read_b32 on the idle LDS pipe). Interp error 3.5e-5, 14x
// below the f16 activation rounding already in the path.
struct __align__(16) SMem {
    f16   W1f[8 * 64 * 8];     // [nt][lane][j]      : TSCL*W1[32+phi1(q,j)][nt*16+mr]
    f16   W2f[8 * 4 * 64 * 8]; // [nt][kt][lane][j]  : TSCL*W2[phi(kt,q,j)][nt*16+mr]
    float B1[H], S1[H], B2[H], B3[D];   // B1,S1,B2 pre-scaled by TSCL
    float TY[TN + 1];          // tanh-of-prescaled table (f32)
    float TD[TN + 1];          // forward differences TY[i+1]-TY[i]
};

// phi(kt,q,j) = (2kt + j/4)*16 + q*4 + j%4 ; phi1(q,j) = (j/4)*16 + q*4 + j%4.
// Identical k-permutation on A (staged weights) and B (C-layout activations)
// -> MFMA k-sum invariant. Zero activation LDS traffic, zero shuffles.
//
// REGISTER MODEL (measured R3..R13):
//  * ~124 arch VGPRs under a 256-reg cap (min-waves=2). ANY tighter cap
//    spills GBs (R6/R9/R10 caps 85/64/32; R11 cap 128 -> 64 VGPR + 2.5 GB
//    scratch, 862 us). Keep __launch_bounds__(256, 2). BT=512 strictly worse
//    (R12: 1 block resident, occ 23.6%).
//  * W3 fragments: 8 x f16x8 = 32 VGPRs/lane, persistent per bijector; all
//    indices compile-time (full unroll) — runtime indexing => scratch.
//  * W1/W2 nt-loops at `#pragma unroll 1` or 2 ONLY: full unroll hoists all
//    ds_read_b128 weight fragments (32 in flight = 128 VGPRs) -> GB-scale
//    spill (R4: 7.4 GB, R7: 7.6 GB). unroll 2 keeps <=2 iterations in flight.

// tanh lookup on prescaled v: 7 full-rate VALU + 2 LDS reads (shared addr reg,
// TY/TD at fixed struct offsets -> ds_read offset immediates).
__device__ __forceinline__ float tanh_lut(const float* __restrict__ TY,
                                          const float* __restrict__ TD, float v) {
    float u = fmaf(v, (float)TN * (1.f / 28.f), (float)TN * 0.5f);
    u = fmaxf(0.f, fminf(u, (float)TN - 0.0625f));   // med3; edges round to +-1 in f16
    float fl = floorf(u);
    float f  = u - fl;
    int   i  = (int)fl;
    return fmaf(f, TD[i], TY[i]);
}
__device__ __forceinline__ uint tanh_pk_lut(const float* __restrict__ TY,
                                            const float* __restrict__ TD,
                                            float a, float b) {
    return pku(tanh_lut(TY, TD, a), tanh_lut(TY, TD, b));
}

__global__ __launch_bounds__(BT, 2) void ffjord_mfma(
    const float* __restrict__ x_in,
    const float* __restrict__ W1, const float* __restrict__ b1,
    const float* __restrict__ W2, const float* __restrict__ b2,
    const float* __restrict__ W3, const float* __restrict__ b3,
    float* __restrict__ out)
{
    __shared__ SMem sm;

    const int tid  = threadIdx.x;
    const int lane = tid & 63;
    const int mrow = lane & 15;      // my sample within the wave tile
    const int quad = lane >> 4;      // k/feature quad
    const int wid  = tid >> 6;
    const int sidx = blockIdx.x * 64 + wid * 16 + mrow;   // my sample (global)

    // Distributed state: x[nt*4 + r] = value[feature nt*16+quad*4+r][sample sidx]
    // k1..k5 packed f16x2: ksp[i][j] holds (elem 2j, 2j+1).
    float x[8];
    uint  ksp[5][4];
    uint  by[4];      // packed f16 y — layer-1 B fragment (IS the eval input)

    #pragma unroll
    for (int nt = 0; nt < 2; ++nt) {
        f32x4 v = *(const f32x4*)(x_in + (size_t)sidx*D + nt*16 + quad*4);
        #pragma unroll
        for (int r = 0; r < 4; ++r) x[nt*4 + r] = v[r];
    }

    // ---- one-time tanh LUT build (exact f32 division; one-time cost) ----
    #pragma unroll 1
    for (int i = tid; i <= TN; i += BT) {
        float v0 = -14.f + (28.f / TN) * i;
        float y0 = 1.f - 2.f / (1.f + __builtin_amdgcn_exp2f(v0));
        float y1 = 1.f - 2.f / (1.f + __builtin_amdgcn_exp2f(v0 + 28.f / TN));
        sm.TY[i] = y0;
        sm.TD[i] = y1 - y0;
    }
    const float* TY = sm.TY;
    const float* TD = sm.TD;

    const float dt = 0.125f;

    for (int bij = 0; bij < NB; ++bij) {
        const float* W1b = W1 + (size_t)bij * 2*D*H;
        const float* b1b = b1 + bij*H;
        const float* W2b = W2 + (size_t)bij * H*H;
        const float* b2b = b2 + bij*H;
        const float* W3b = W3 + (size_t)bij * H*D;
        const float* b3b = b3 + bij*D;

        __syncthreads();  // prior bijector done reading weights (also fences LUT build)
        // ---- stage weights: fragment-order, k-permuted, f16, tanh-prescaled ----
        #pragma unroll 1
        for (int g = tid; g < 8*64; g += BT) {               // W1f (x TSCL)
            int nt = g >> 6, ln = g & 63, q = (ln >> 4) & 3, mr = ln & 15;
            f16 tmp[8];
            #pragma unroll
            for (int j = 0; j < 8; ++j) {
                int feat = ((j >> 2) << 4) + q*4 + (j & 3);  // phi1
                tmp[j] = (f16)(W1b[(size_t)(D + feat)*H + nt*16 + mr] * TSCL);
            }
            *(f16x8*)&sm.W1f[(size_t)g * 8] = *(f16x8*)tmp;
        }
        #pragma unroll 1
        for (int g = tid; g < 8*4*64; g += BT) {             // W2f (x TSCL)
            int nt = g >> 8, kt = (g >> 6) & 3, ln = g & 63, q = (ln >> 4) & 3, mr = ln & 15;
            f16 tmp[8];
            #pragma unroll
            for (int j = 0; j < 8; ++j) {
                int feat = (2*kt + (j >> 2))*16 + q*4 + (j & 3);  // phi
                tmp[j] = (f16)(W2b[(size_t)feat*H + nt*16 + mr] * TSCL);
            }
            *(f16x8*)&sm.W2f[(size_t)g * 8] = *(f16x8*)tmp;
        }
        #pragma unroll 1
        for (int n = tid; n < H; n += BT) {                  // biases + t-fold sums (x TSCL)
            float s = 0.f;
            for (int i = 0; i < D; ++i) s += W1b[(size_t)i*H + n];
            sm.S1[n] = s * TSCL; sm.B1[n] = b1b[n] * TSCL; sm.B2[n] = b2b[n] * TSCL;
        }
        if (tid < D) sm.B3[tid] = b3b[tid];

        // ---- W3 fragments -> REGISTERS (8 x f16x8 = 32 VGPRs, per-lane) ----
        f16x8 w3r[2][4];
        #pragma unroll
        for (int nt = 0; nt < 2; ++nt)
            #pragma unroll
            for (int kt = 0; kt < 4; ++kt) {
                f16 tmp[8];
                #pragma unroll
                for (int j = 0; j < 8; ++j) {
                    int feat = (2*kt + (j >> 2))*16 + quad*4 + (j & 3);  // phi
                    tmp[j] = (f16)W3b[(size_t)feat*D + nt*16 + mrow];
                }
                w3r[nt][kt] = *(f16x8*)tmp;
            }
        __syncthreads();

        // y := x  (packed)
        #pragma unroll
        for (int p = 0; p < 4; ++p)
            by[p] = pku(x[2*p], x[2*p + 1]);

        for (int step = 0; step < NSTEPS; ++step) {
            const float t0 = step * dt;
            #pragma unroll 1
            for (int s = 0; s < 6; ++s) {
                const float te = t0 + dt * CC[s];

                // ============ EVAL (registers + conflict-free weight LDS) ============
                // layer 1 (K=32): C init = (b1 + te*S1)*TSCL (t-concat + tanh scale folded)
                uint ph1[16];
                {
                    union { f16x8 v; uint u[4]; } b;
                    b.u[0] = by[0]; b.u[1] = by[1]; b.u[2] = by[2]; b.u[3] = by[3];
                    #pragma unroll 2
                    for (int nt = 0; nt < 8; ++nt) {
                        f16x8 wf = *(const f16x8*)&sm.W1f[(nt*64 + lane)*8];
                        f32x4 bv = *(const f32x4*)&sm.B1[nt*16 + quad*4];
                        f32x4 sv = *(const f32x4*)&sm.S1[nt*16 + quad*4];
                        f32x4 ci;
                        #pragma unroll
                        for (int r = 0; r < 4; ++r) ci[r] = fmaf(te, sv[r], bv[r]);
                        f32x4 acc = __builtin_amdgcn_mfma_f32_16x16x32_f16(wf, b.v, ci, 0, 0, 0);
                        ph1[nt*2+0] = tanh_pk_lut(TY, TD, acc[0], acc[1]);
                        ph1[nt*2+1] = tanh_pk_lut(TY, TD, acc[2], acc[3]);
                    }
                }
                // layer 2 (K=128): B operands built ONCE (nt-invariant), reused 8x
                uint ph2[16];
                {
                    f16x8 bb[4];
                    #pragma unroll
                    for (int kt = 0; kt < 4; ++kt) {
                        union { f16x8 v; uint u[4]; } b;
                        b.u[0] = ph1[kt*4+0]; b.u[1] = ph1[kt*4+1];
                        b.u[2] = ph1[kt*4+2]; b.u[3] = ph1[kt*4+3];
                        bb[kt] = b.v;
                    }
                    #pragma unroll 2
                    for (int nt = 0; nt < 8; ++nt) {
                        f32x4 acc = *(const f32x4*)&sm.B2[nt*16 + quad*4];
                        #pragma unroll
                        for (int kt = 0; kt < 4; ++kt) {
                            f16x8 wf = *(const f16x8*)&sm.W2f[((nt*4 + kt)*64 + lane)*8];
                            acc = __builtin_amdgcn_mfma_f32_16x16x32_f16(wf, bb[kt], acc, 0, 0, 0);
                        }
                        ph2[nt*2+0] = tanh_pk_lut(TY, TD, acc[0], acc[1]);
                        ph2[nt*2+1] = tanh_pk_lut(TY, TD, acc[2], acc[3]);
                    }
                }
                // layer 3 (K=128, Nout=32): A operands resident registers; B built once.
                float kd[8];
                {
                    f16x8 bb[4];
                    #pragma unroll
                    for (int kt = 0; kt < 4; ++kt) {
                        union { f16x8 v; uint u[4]; } b;
                        b.u[0] = ph2[kt*4+0]; b.u[1] = ph2[kt*4+1];
                        b.u[2] = ph2[kt*4+2]; b.u[3] = ph2[kt*4+3];
                        bb[kt] = b.v;
                    }
                    #pragma unroll
                    for (int nt = 0; nt < 2; ++nt) {
                        f32x4 acc = *(const f32x4*)&sm.B3[nt*16 + quad*4];
                        #pragma unroll
                        for (int kt = 0; kt < 4; ++kt)
                            acc = __builtin_amdgcn_mfma_f32_16x16x32_f16(w3r[nt][kt], bb[kt], acc, 0, 0, 0);
                        #pragma unroll
                        for (int r = 0; r < 4; ++r) kd[nt*4 + r] = acc[r];
                    }
                }

                // ===== DOPRI combine; k-history packed f16, y kept only packed =====
                switch (s) {
                case 0:
                    #pragma unroll
                    for (int j = 0; j < 4; ++j) {
                        ksp[0][j] = pku(kd[2*j], kd[2*j+1]);
                        float ya = fmaf(dt*0.2f, kd[2*j],   x[2*j]);
                        float yb = fmaf(dt*0.2f, kd[2*j+1], x[2*j+1]);
                        by[j] = pku(ya, yb);
                    }
                    break;
                case 1:
                    #pragma unroll
                    for (int j = 0; j < 4; ++j) {
                        ksp[1][j] = pku(kd[2*j], kd[2*j+1]);
                        float ya = x[2*j]   + dt*((3.f/40.f)*lo32(ksp[0][j]) + (9.f/40.f)*kd[2*j]);
                        float yb = x[2*j+1] + dt*((3.f/40.f)*hi32(ksp[0][j]) + (9.f/40.f)*kd[2*j+1]);
                        by[j] = pku(ya, yb);
                    }
                    break;
                case 2:
                    #pragma unroll
                    for (int j = 0; j < 4; ++j) {
                        ksp[2][j] = pku(kd[2*j], kd[2*j+1]);
                        float ya = x[2*j]   + dt*((44.f/45.f)*lo32(ksp[0][j]) - (56.f/15.f)*lo32(ksp[1][j]) + (32.f/9.f)*kd[2*j]);
                        float yb = x[2*j+1] + dt*((44.f/45.f)*hi32(ksp[0][j]) - (56.f/15.f)*hi32(ksp[1][j]) + (32.f/9.f)*kd[2*j+1]);
                        by[j] = pku(ya, yb);
                    }
                    break;
                case 3:
                    #pragma unroll
                    for (int j = 0; j < 4; ++j) {
                        ksp[3][j] = pku(kd[2*j], kd[2*j+1]);
                        float ya = x[2*j]   + dt*((19372.f/6561.f)*lo32(ksp[0][j]) - (25360.f/2187.f)*lo32(ksp[1][j])
                                                + (64448.f/6561.f)*lo32(ksp[2][j]) - (212.f/729.f)*kd[2*j]);
                        float yb = x[2*j+1] + dt*((19372.f/6561.f)*hi32(ksp[0][j]) - (25360.f/2187.f)*hi32(ksp[1][j])
                                                + (64448.f/6561.f)*hi32(ksp[2][j]) - (212.f/729.f)*kd[2*j+1]);
                        by[j] = pku(ya, yb);
                    }
                    break;
                case 4:
                    #pragma unroll
                    for (int j = 0; j < 4; ++j) {
                        ksp[4][j] = pku(kd[2*j], kd[2*j+1]);
                        float ya = x[2*j]   + dt*((9017.f/3168.f)*lo32(ksp[0][j]) - (355.f/33.f)*lo32(ksp[1][j])
                                                + (46732.f/5247.f)*lo32(ksp[2][j]) + (49.f/176.f)*lo32(ksp[3][j])
                                                - (5103.f/18656.f)*kd[2*j]);
                        float yb = x[2*j+1] + dt*((9017.f/3168.f)*hi32(ksp[0][j]) - (355.f/33.f)*hi32(ksp[1][j])
                                                + (46732.f/5247.f)*hi32(ksp[2][j]) + (49.f/176.f)*hi32(ksp[3][j])
                                                - (5103.f/18656.f)*kd[2*j+1]);
                        by[j] = pku(ya, yb);
                    }
                    break;
                default:
                    #pragma unroll
                    for (int j = 0; j < 4; ++j) {
                        float xa = x[2*j]   + dt*((35.f/384.f)*lo32(ksp[0][j]) + (500.f/1113.f)*lo32(ksp[2][j])
                                                + (125.f/192.f)*lo32(ksp[3][j]) - (2187.f/6784.f)*lo32(ksp[4][j])
                                                + (11.f/84.f)*kd[2*j]);
                        float xb = x[2*j+1] + dt*((35.f/384.f)*hi32(ksp[0][j]) + (500.f/1113.f)*hi32(ksp[2][j])
                                                + (125.f/192.f)*hi32(ksp[3][j]) - (2187.f/6784.f)*hi32(ksp[4][j])
                                                + (11.f/84.f)*kd[2*j+1]);
                        x[2*j] = xa; x[2*j+1] = xb;
                        by[j] = pku(xa, xb);
                    }
                    break;
                }
            } // stages
        } // steps
    } // bijectors

    #pragma unroll
    for (int nt = 0; nt < 2; ++nt) {
        f32x4 v;
        #pragma unroll
        for (int r = 0; r < 4; ++r) v[r] = x[nt*4 + r];
        *(f32x4*)(out + (size_t)sidx*D + nt*16 + quad*4) = v;
    }
}

extern "C" void kernel_launch(void* const* d_in, const int* in_sizes, int n_in,
                              void* d_out, int out_size, void* d_ws, size_t ws_size,
                              hipStream_t stream) {
    (void)d_ws; (void)ws_size; (void)n_in; (void)out_size;
    const float* x  = (const float*)d_in[0];
    const float* W1 = (const float*)d_in[1];
    const float* b1 = (const float*)d_in[2];
    const float* W2 = (const float*)d_in[3];
    const float* b2 = (const float*)d_in[4];
    const float* W3 = (const float*)d_in[5];
    const float* b3 = (const float*)d_in[6];
    float* out = (float*)d_out;

    const int n = in_sizes[0] / D;          // 65536 samples
    const int grid = n / 64;                // 1024 blocks (64 samples each), exact
    ffjord_mfma<<<grid, BT, 0, stream>>>(x, W1, b1, W2, b2, W3, b3, out);
}

// Round 5
// 710.247 us; speedup vs baseline: 1.3663x; 1.3663x over previous
//
#include <hip/hip_runtime.h>

#define NB 2
#define D 32
#define H 128
#define NSTEPS 8
#define BT 256

typedef _Float16 f16;
typedef _Float16 f16x2 __attribute__((ext_vector_type(2)));
typedef _Float16 f16x8 __attribute__((ext_vector_type(8)));
typedef float    f32x4 __attribute__((ext_vector_type(4)));
typedef unsigned int uint;

// Weights/biases feeding a tanh are pre-scaled by 2*log2(e) at staging time, so
// the MFMA accumulator is already v = 2*log2e*z and tanh needs no multiply:
#define TSCL 2.8853900817779268f

__device__ __forceinline__ float fast_tanh_pre(float v) {
    // v = 2*log2e*z. tanh(z) = 1 - 2/(1+2^v); exp2 saturates -> exact +-1 limits.
    float e = __builtin_amdgcn_exp2f(v);
    return 1.f - 2.f * __builtin_amdgcn_rcpf(1.f + e);
}
__device__ __forceinline__ uint tanh_pk(float a, float b) {
    return __builtin_bit_cast(uint, __builtin_amdgcn_cvt_pkrtz(fast_tanh_pre(a), fast_tanh_pre(b)));
}
__device__ __forceinline__ uint pku(float a, float b) {
    return __builtin_bit_cast(uint, __builtin_amdgcn_cvt_pkrtz(a, b));
}
__device__ __forceinline__ float lo32(uint u) { return (float)__builtin_bit_cast(f16x2, u)[0]; }
__device__ __forceinline__ float hi32(uint u) { return (float)__builtin_bit_cast(f16x2, u)[1]; }

__device__ const float CC[6] = {0.f, 0.2f, 0.3f, 0.8f, 8.f/9.f, 1.f};

// LDS: weights only, fragment-ordered & k-permuted. 51,200 B (W3 back in LDS:
// R3 proved reg-W3 neutral; LDS-W3 frees 32 VGPRs for the dual-sample state).
//
// BOTTLENECK MODEL (R0..R14 measured):
//  * Occupancy engineering moved occ 21..40% both directions; dur pinned
//    747..862 -> occupancy is NOT the lever.
//  * VALU-issue model fits: ~272 full-rate VALU (2cyc) + 128 trans (16cyc)
//    = ~2700 issue-cyc/wave/stage; trans (tanh exp2+rcp) = 2/3 of issue.
//    Floor at 100% VALUBusy ~433 us; measured 58% busy.
//  * R14 LUT-tanh: REGRESSED 746->970. 1.77e8 LDS bank conflicts (random
//    gather) + compiled to MORE issue slots than 2 trans ops. Padé-rational
//    (rcp-based) and ldexp-exp2 also compute to >=current 36 cyc -> per-op
//    tanh cost is already near-optimal. Lever = latency hiding, not op count.
//  * THIS ROUND: 2 samples/thread (wave = 32 samples). Doubles independent
//    tanh chains 4->8 per cluster + reuses every weight ds_read 2x. Grid 512.
struct __align__(16) SMem {
    f16   W1f[8 * 64 * 8];     // [nt][lane][j]      : TSCL*W1[32+phi1(q,j)][nt*16+mr]
    f16   W2f[8 * 4 * 64 * 8]; // [nt][kt][lane][j]  : TSCL*W2[phi(kt,q,j)][nt*16+mr]
    f16   W3f[2 * 4 * 64 * 8]; // [nt][kt][lane][j]  : W3[phi(kt,q,j)][nt*16+mr] (unscaled)
    float B1[H], S1[H], B2[H], B3[D];   // B1,S1,B2 pre-scaled by TSCL
};

// phi(kt,q,j) = (2kt + j/4)*16 + q*4 + j%4 ; phi1(q,j) = (j/4)*16 + q*4 + j%4.
// Identical k-permutation on A (staged weights) and B (C-layout activations)
// -> MFMA k-sum invariant. Zero activation LDS traffic, zero shuffles.
//
// REGISTER MODEL (measured R3..R14):
//  * __launch_bounds__(256, 2) (cap 256) ONLY. Tighter caps spill GBs
//    (R6/R9/R10 caps 85/64/32; R11 cap 128 -> 64 VGPR + 2.5 GB scratch).
//  * nt-loops at `#pragma unroll 1` or 2 ONLY: full unroll hoists all
//    ds_read_b128 weight fragments -> GB-scale spill (R4: 7.4 GB, R7: 7.6 GB).
//  * Dual-sample state: x 16 + ksp 40 + by 8 + eval temporaries; expect
//    ~170-210 VGPR. WRITE_SIZE is the spill tripwire (must stay ~20 MB).

// DOPRI stage combines (per 2-elem packed lane j), parameterized by sample.
#define DOP0(x_, ksp_, by_, kd_) \
    _Pragma("unroll") for (int j = 0; j < 4; ++j) { \
        ksp_[0][j] = pku(kd_[2*j], kd_[2*j+1]); \
        float ya = fmaf(dt*0.2f, kd_[2*j],   x_[2*j]); \
        float yb = fmaf(dt*0.2f, kd_[2*j+1], x_[2*j+1]); \
        by_[j] = pku(ya, yb); }

#define DOP1(x_, ksp_, by_, kd_) \
    _Pragma("unroll") for (int j = 0; j < 4; ++j) { \
        ksp_[1][j] = pku(kd_[2*j], kd_[2*j+1]); \
        float ya = x_[2*j]   + dt*((3.f/40.f)*lo32(ksp_[0][j]) + (9.f/40.f)*kd_[2*j]); \
        float yb = x_[2*j+1] + dt*((3.f/40.f)*hi32(ksp_[0][j]) + (9.f/40.f)*kd_[2*j+1]); \
        by_[j] = pku(ya, yb); }

#define DOP2(x_, ksp_, by_, kd_) \
    _Pragma("unroll") for (int j = 0; j < 4; ++j) { \
        ksp_[2][j] = pku(kd_[2*j], kd_[2*j+1]); \
        float ya = x_[2*j]   + dt*((44.f/45.f)*lo32(ksp_[0][j]) - (56.f/15.f)*lo32(ksp_[1][j]) + (32.f/9.f)*kd_[2*j]); \
        float yb = x_[2*j+1] + dt*((44.f/45.f)*hi32(ksp_[0][j]) - (56.f/15.f)*hi32(ksp_[1][j]) + (32.f/9.f)*kd_[2*j+1]); \
        by_[j] = pku(ya, yb); }

#define DOP3(x_, ksp_, by_, kd_) \
    _Pragma("unroll") for (int j = 0; j < 4; ++j) { \
        ksp_[3][j] = pku(kd_[2*j], kd_[2*j+1]); \
        float ya = x_[2*j]   + dt*((19372.f/6561.f)*lo32(ksp_[0][j]) - (25360.f/2187.f)*lo32(ksp_[1][j]) \
                                + (64448.f/6561.f)*lo32(ksp_[2][j]) - (212.f/729.f)*kd_[2*j]); \
        float yb = x_[2*j+1] + dt*((19372.f/6561.f)*hi32(ksp_[0][j]) - (25360.f/2187.f)*hi32(ksp_[1][j]) \
                                + (64448.f/6561.f)*hi32(ksp_[2][j]) - (212.f/729.f)*kd_[2*j+1]); \
        by_[j] = pku(ya, yb); }

#define DOP4(x_, ksp_, by_, kd_) \
    _Pragma("unroll") for (int j = 0; j < 4; ++j) { \
        ksp_[4][j] = pku(kd_[2*j], kd_[2*j+1]); \
        float ya = x_[2*j]   + dt*((9017.f/3168.f)*lo32(ksp_[0][j]) - (355.f/33.f)*lo32(ksp_[1][j]) \
                                + (46732.f/5247.f)*lo32(ksp_[2][j]) + (49.f/176.f)*lo32(ksp_[3][j]) \
                                - (5103.f/18656.f)*kd_[2*j]); \
        float yb = x_[2*j+1] + dt*((9017.f/3168.f)*hi32(ksp_[0][j]) - (355.f/33.f)*hi32(ksp_[1][j]) \
                                + (46732.f/5247.f)*hi32(ksp_[2][j]) + (49.f/176.f)*hi32(ksp_[3][j]) \
                                - (5103.f/18656.f)*kd_[2*j+1]); \
        by_[j] = pku(ya, yb); }

#define DOP5(x_, ksp_, by_, kd_) \
    _Pragma("unroll") for (int j = 0; j < 4; ++j) { \
        float xa = x_[2*j]   + dt*((35.f/384.f)*lo32(ksp_[0][j]) + (500.f/1113.f)*lo32(ksp_[2][j]) \
                                + (125.f/192.f)*lo32(ksp_[3][j]) - (2187.f/6784.f)*lo32(ksp_[4][j]) \
                                + (11.f/84.f)*kd_[2*j]); \
        float xb = x_[2*j+1] + dt*((35.f/384.f)*hi32(ksp_[0][j]) + (500.f/1113.f)*hi32(ksp_[2][j]) \
                                + (125.f/192.f)*hi32(ksp_[3][j]) - (2187.f/6784.f)*hi32(ksp_[4][j]) \
                                + (11.f/84.f)*kd_[2*j+1]); \
        x_[2*j] = xa; x_[2*j+1] = xb; \
        by_[j] = pku(xa, xb); }

__global__ __launch_bounds__(BT, 2) void ffjord_mfma(
    const float* __restrict__ x_in,
    const float* __restrict__ W1, const float* __restrict__ b1,
    const float* __restrict__ W2, const float* __restrict__ b2,
    const float* __restrict__ W3, const float* __restrict__ b3,
    float* __restrict__ out)
{
    __shared__ SMem sm;

    const int tid  = threadIdx.x;
    const int lane = tid & 63;
    const int mrow = lane & 15;      // my sample within the wave tile
    const int quad = lane >> 4;      // k/feature quad
    const int wid  = tid >> 6;
    // Two samples per thread: A and B tiles are independent 16-sample MFMA
    // B-fragments sharing every weight fragment / C-init.
    const int sidxA = blockIdx.x * 128 + wid * 32 + mrow;
    const int sidxB = sidxA + 16;

    float xA[8], xB[8];
    uint  kspA[5][4], kspB[5][4];
    uint  byA[4], byB[4];

    #pragma unroll
    for (int nt = 0; nt < 2; ++nt) {
        f32x4 va = *(const f32x4*)(x_in + (size_t)sidxA*D + nt*16 + quad*4);
        f32x4 vb = *(const f32x4*)(x_in + (size_t)sidxB*D + nt*16 + quad*4);
        #pragma unroll
        for (int r = 0; r < 4; ++r) { xA[nt*4 + r] = va[r]; xB[nt*4 + r] = vb[r]; }
    }

    const float dt = 0.125f;

    for (int bij = 0; bij < NB; ++bij) {
        const float* W1b = W1 + (size_t)bij * 2*D*H;
        const float* b1b = b1 + bij*H;
        const float* W2b = W2 + (size_t)bij * H*H;
        const float* b2b = b2 + bij*H;
        const float* W3b = W3 + (size_t)bij * H*D;
        const float* b3b = b3 + bij*D;

        __syncthreads();  // prior bijector done reading weights
        // ---- stage weights: fragment-order, k-permuted, f16, tanh-prescaled ----
        #pragma unroll 1
        for (int g = tid; g < 8*64; g += BT) {               // W1f (x TSCL)
            int nt = g >> 6, ln = g & 63, q = (ln >> 4) & 3, mr = ln & 15;
            f16 tmp[8];
            #pragma unroll
            for (int j = 0; j < 8; ++j) {
                int feat = ((j >> 2) << 4) + q*4 + (j & 3);  // phi1
                tmp[j] = (f16)(W1b[(size_t)(D + feat)*H + nt*16 + mr] * TSCL);
            }
            *(f16x8*)&sm.W1f[(size_t)g * 8] = *(f16x8*)tmp;
        }
        #pragma unroll 1
        for (int g = tid; g < 8*4*64; g += BT) {             // W2f (x TSCL)
            int nt = g >> 8, kt = (g >> 6) & 3, ln = g & 63, q = (ln >> 4) & 3, mr = ln & 15;
            f16 tmp[8];
            #pragma unroll
            for (int j = 0; j < 8; ++j) {
                int feat = (2*kt + (j >> 2))*16 + q*4 + (j & 3);  // phi
                tmp[j] = (f16)(W2b[(size_t)feat*H + nt*16 + mr] * TSCL);
            }
            *(f16x8*)&sm.W2f[(size_t)g * 8] = *(f16x8*)tmp;
        }
        #pragma unroll 1
        for (int g = tid; g < 2*4*64; g += BT) {             // W3f (unscaled)
            int nt = g >> 8, kt = (g >> 6) & 3, ln = g & 63, q = (ln >> 4) & 3, mr = ln & 15;
            f16 tmp[8];
            #pragma unroll
            for (int j = 0; j < 8; ++j) {
                int feat = (2*kt + (j >> 2))*16 + q*4 + (j & 3);  // phi
                tmp[j] = (f16)W3b[(size_t)feat*D + nt*16 + mr];
            }
            *(f16x8*)&sm.W3f[(size_t)g * 8] = *(f16x8*)tmp;
        }
        #pragma unroll 1
        for (int n = tid; n < H; n += BT) {                  // biases + t-fold sums (x TSCL)
            float s = 0.f;
            for (int i = 0; i < D; ++i) s += W1b[(size_t)i*H + n];
            sm.S1[n] = s * TSCL; sm.B1[n] = b1b[n] * TSCL; sm.B2[n] = b2b[n] * TSCL;
        }
        if (tid < D) sm.B3[tid] = b3b[tid];
        __syncthreads();

        // y := x  (packed)
        #pragma unroll
        for (int p = 0; p < 4; ++p) {
            byA[p] = pku(xA[2*p], xA[2*p + 1]);
            byB[p] = pku(xB[2*p], xB[2*p + 1]);
        }

        for (int step = 0; step < NSTEPS; ++step) {
            const float t0 = step * dt;
            #pragma unroll 1
            for (int s = 0; s < 6; ++s) {
                const float te = t0 + dt * CC[s];

                // ============ EVAL: two samples share every weight fragment ============
                // layer 1 (K=32): C init = (b1 + te*S1)*TSCL — sample-independent
                uint ph1a[16], ph1b[16];
                {
                    union { f16x8 v; uint u[4]; } ba, bb;
                    ba.u[0] = byA[0]; ba.u[1] = byA[1]; ba.u[2] = byA[2]; ba.u[3] = byA[3];
                    bb.u[0] = byB[0]; bb.u[1] = byB[1]; bb.u[2] = byB[2]; bb.u[3] = byB[3];
                    #pragma unroll 2
                    for (int nt = 0; nt < 8; ++nt) {
                        f16x8 wf = *(const f16x8*)&sm.W1f[(nt*64 + lane)*8];
                        f32x4 bv = *(const f32x4*)&sm.B1[nt*16 + quad*4];
                        f32x4 sv = *(const f32x4*)&sm.S1[nt*16 + quad*4];
                        f32x4 ci;
                        #pragma unroll
                        for (int r = 0; r < 4; ++r) ci[r] = fmaf(te, sv[r], bv[r]);
                        f32x4 accA = __builtin_amdgcn_mfma_f32_16x16x32_f16(wf, ba.v, ci, 0, 0, 0);
                        f32x4 accB = __builtin_amdgcn_mfma_f32_16x16x32_f16(wf, bb.v, ci, 0, 0, 0);
                        ph1a[nt*2+0] = tanh_pk(accA[0], accA[1]);
                        ph1a[nt*2+1] = tanh_pk(accA[2], accA[3]);
                        ph1b[nt*2+0] = tanh_pk(accB[0], accB[1]);
                        ph1b[nt*2+1] = tanh_pk(accB[2], accB[3]);
                    }
                }
                // layer 2 (K=128): weight fragment ds_read reused for A and B
                uint ph2a[16], ph2b[16];
                {
                    f16x8 bba[4], bbb[4];
                    #pragma unroll
                    for (int kt = 0; kt < 4; ++kt) {
                        union { f16x8 v; uint u[4]; } a, b;
                        a.u[0] = ph1a[kt*4+0]; a.u[1] = ph1a[kt*4+1];
                        a.u[2] = ph1a[kt*4+2]; a.u[3] = ph1a[kt*4+3];
                        b.u[0] = ph1b[kt*4+0]; b.u[1] = ph1b[kt*4+1];
                        b.u[2] = ph1b[kt*4+2]; b.u[3] = ph1b[kt*4+3];
                        bba[kt] = a.v; bbb[kt] = b.v;
                    }
                    #pragma unroll 2
                    for (int nt = 0; nt < 8; ++nt) {
                        f32x4 c0 = *(const f32x4*)&sm.B2[nt*16 + quad*4];
                        f32x4 accA = c0, accB = c0;
                        #pragma unroll
                        for (int kt = 0; kt < 4; ++kt) {
                            f16x8 wf = *(const f16x8*)&sm.W2f[((nt*4 + kt)*64 + lane)*8];
                            accA = __builtin_amdgcn_mfma_f32_16x16x32_f16(wf, bba[kt], accA, 0, 0, 0);
                            accB = __builtin_amdgcn_mfma_f32_16x16x32_f16(wf, bbb[kt], accB, 0, 0, 0);
                        }
                        ph2a[nt*2+0] = tanh_pk(accA[0], accA[1]);
                        ph2a[nt*2+1] = tanh_pk(accA[2], accA[3]);
                        ph2b[nt*2+0] = tanh_pk(accB[0], accB[1]);
                        ph2b[nt*2+1] = tanh_pk(accB[2], accB[3]);
                    }
                }
                // layer 3 (K=128, Nout=32)
                float kda[8], kdb[8];
                {
                    f16x8 bba[4], bbb[4];
                    #pragma unroll
                    for (int kt = 0; kt < 4; ++kt) {
                        union { f16x8 v; uint u[4]; } a, b;
                        a.u[0] = ph2a[kt*4+0]; a.u[1] = ph2a[kt*4+1];
                        a.u[2] = ph2a[kt*4+2]; a.u[3] = ph2a[kt*4+3];
                        b.u[0] = ph2b[kt*4+0]; b.u[1] = ph2b[kt*4+1];
                        b.u[2] = ph2b[kt*4+2]; b.u[3] = ph2b[kt*4+3];
                        bba[kt] = a.v; bbb[kt] = b.v;
                    }
                    #pragma unroll 1
                    for (int nt = 0; nt < 2; ++nt) {
                        f32x4 c0 = *(const f32x4*)&sm.B3[nt*16 + quad*4];
                        f32x4 accA = c0, accB = c0;
                        #pragma unroll
                        for (int kt = 0; kt < 4; ++kt) {
                            f16x8 wf = *(const f16x8*)&sm.W3f[((nt*4 + kt)*64 + lane)*8];
                            accA = __builtin_amdgcn_mfma_f32_16x16x32_f16(wf, bba[kt], accA, 0, 0, 0);
                            accB = __builtin_amdgcn_mfma_f32_16x16x32_f16(wf, bbb[kt], accB, 0, 0, 0);
                        }
                        #pragma unroll
                        for (int r = 0; r < 4; ++r) { kda[nt*4 + r] = accA[r]; kdb[nt*4 + r] = accB[r]; }
                    }
                }

                // ===== DOPRI combine (both samples) =====
                switch (s) {
                case 0:  DOP0(xA, kspA, byA, kda) DOP0(xB, kspB, byB, kdb) break;
                case 1:  DOP1(xA, kspA, byA, kda) DOP1(xB, kspB, byB, kdb) break;
                case 2:  DOP2(xA, kspA, byA, kda) DOP2(xB, kspB, byB, kdb) break;
                case 3:  DOP3(xA, kspA, byA, kda) DOP3(xB, kspB, byB, kdb) break;
                case 4:  DOP4(xA, kspA, byA, kda) DOP4(xB, kspB, byB, kdb) break;
                default: DOP5(xA, kspA, byA, kda) DOP5(xB, kspB, byB, kdb) break;
                }
            } // stages
        } // steps
    } // bijectors

    #pragma unroll
    for (int nt = 0; nt < 2; ++nt) {
        f32x4 va, vb;
        #pragma unroll
        for (int r = 0; r < 4; ++r) { va[r] = xA[nt*4 + r]; vb[r] = xB[nt*4 + r]; }
        *(f32x4*)(out + (size_t)sidxA*D + nt*16 + quad*4) = va;
        *(f32x4*)(out + (size_t)sidxB*D + nt*16 + quad*4) = vb;
    }
}

extern "C" void kernel_launch(void* const* d_in, const int* in_sizes, int n_in,
                              void* d_out, int out_size, void* d_ws, size_t ws_size,
                              hipStream_t stream) {
    (void)d_ws; (void)ws_size; (void)n_in; (void)out_size;
    const float* x  = (const float*)d_in[0];
    const float* W1 = (const float*)d_in[1];
    const float* b1 = (const float*)d_in[2];
    const float* W2 = (const float*)d_in[3];
    const float* b2 = (const float*)d_in[4];
    const float* W3 = (const float*)d_in[5];
    const float* b3 = (const float*)d_in[6];
    float* out = (float*)d_out;

    const int n = in_sizes[0] / D;          // 65536 samples
    const int grid = n / 128;               // 512 blocks (128 samples each), exact
    ffjord_mfma<<<grid, BT, 0, stream>>>(x, W1, b1, W2, b2, W3, b3, out);
}

// Round 6
// 660.281 us; speedup vs baseline: 1.4697x; 1.0757x over previous
//
#include <hip/hip_runtime.h>

#define NB 2
#define D 32
#define H 128
#define NSTEPS 8
#define BT 256

typedef _Float16 f16;
typedef _Float16 f16x2 __attribute__((ext_vector_type(2)));
typedef _Float16 f16x8 __attribute__((ext_vector_type(8)));
typedef float    f32x4 __attribute__((ext_vector_type(4)));
typedef unsigned int uint;
typedef uint uintx4 __attribute__((ext_vector_type(4)));

// Weights/biases feeding a tanh are pre-scaled by 2*log2(e) at staging time, so
// the MFMA accumulator is already v = 2*log2e*z and tanh needs no multiply:
#define TSCL 2.8853900817779268f

__device__ __forceinline__ float fast_tanh_pre(float v) {
    // v = 2*log2e*z. tanh(z) = 1 - 2/(1+2^v); exp2 saturates -> exact +-1 limits.
    float e = __builtin_amdgcn_exp2f(v);
    return 1.f - 2.f * __builtin_amdgcn_rcpf(1.f + e);
}
__device__ __forceinline__ uint tanh_pk(float a, float b) {
    return __builtin_bit_cast(uint, __builtin_amdgcn_cvt_pkrtz(fast_tanh_pre(a), fast_tanh_pre(b)));
}
__device__ __forceinline__ uint pku(float a, float b) {
    return __builtin_bit_cast(uint, __builtin_amdgcn_cvt_pkrtz(a, b));
}
__device__ __forceinline__ float lo32(uint u) { return (float)__builtin_bit_cast(f16x2, u)[0]; }
__device__ __forceinline__ float hi32(uint u) { return (float)__builtin_bit_cast(f16x2, u)[1]; }

__device__ const float CC[6] = {0.f, 0.2f, 0.3f, 0.8f, 8.f/9.f, 1.f};

// BOTTLENECK MODEL (R0..R15 measured):
//  * Occupancy engineering (R11-R13): occ moved 21..40% both ways, dur pinned
//    -> not the lever. LUT-tanh (R14): REGRESSED (1.77e8 bank conflicts, more
//    issue slots). Dual-sample ILP (R15): WIN 747->710, VALUBusy 58->66.
//  * R15's residual: allocator chose the 128-reg granule (4 waves/SIMD target)
//    despite a 256 cap, spilling ~50 MB/dispatch (WRITE 25->78 MB) AND
//    dropping occupancy 27->20% (scratch caps resident waves).
//  * THIS ROUND: amdgpu_waves_per_eu(2,2) — occupancy >2 waves/EU is
//    unreachable anyway (LDS 51200 -> 2 blocks/CU) so let regalloc use the
//    full 2-wave budget (256) and kill the spill. Plus: B-fragments built
//    directly (no ph[16] double storage) and L3 fused into L2 (each ph2
//    fragment consumed + released per kt).
struct __align__(16) SMem {
    f16   W1f[8 * 64 * 8];     // [nt][lane][j]      : TSCL*W1[32+phi1(q,j)][nt*16+mr]
    f16   W2f[8 * 4 * 64 * 8]; // [nt][kt][lane][j]  : TSCL*W2[phi(kt,q,j)][nt*16+mr]
    f16   W3f[2 * 4 * 64 * 8]; // [nt][kt][lane][j]  : W3[phi(kt,q,j)][nt*16+mr] (unscaled)
    float B1[H], S1[H], B2[H], B3[D];   // B1,S1,B2 pre-scaled by TSCL
};

// phi(kt,q,j) = (2kt + j/4)*16 + q*4 + j%4 ; phi1(q,j) = (j/4)*16 + q*4 + j%4.
// Identical k-permutation on A (staged weights) and B (C-layout activations)
// -> MFMA k-sum invariant. Zero activation LDS traffic, zero shuffles.
//
// REGISTER MODEL (measured R3..R15):
//  * Tight caps spill GBs (R6/R9/R10/R11). R15: even a 256 cap isn't enough —
//    the allocator's occupancy heuristic picked 128+spill; waves_per_eu(2,2)
//    removes the incentive.
//  * Inner weight loops stay at unroll<=2 / unroll 1 so ds_read fragments
//    don't hoist en masse (R4/R7: full unroll -> 7.4/7.6 GB spill).
//  * Fragment arrays (fA1/fB1, a3A/a3B, da/db) are indexed ONLY by fully
//    unrolled vars — runtime indexing demotes to scratch.

// DOPRI stage combines (per 2-elem packed lane j), parameterized by sample.
#define DOP0(x_, ksp_, by_, kd_) \
    _Pragma("unroll") for (int j = 0; j < 4; ++j) { \
        ksp_[0][j] = pku(kd_[2*j], kd_[2*j+1]); \
        float ya = fmaf(dt*0.2f, kd_[2*j],   x_[2*j]); \
        float yb = fmaf(dt*0.2f, kd_[2*j+1], x_[2*j+1]); \
        by_[j] = pku(ya, yb); }

#define DOP1(x_, ksp_, by_, kd_) \
    _Pragma("unroll") for (int j = 0; j < 4; ++j) { \
        ksp_[1][j] = pku(kd_[2*j], kd_[2*j+1]); \
        float ya = x_[2*j]   + dt*((3.f/40.f)*lo32(ksp_[0][j]) + (9.f/40.f)*kd_[2*j]); \
        float yb = x_[2*j+1] + dt*((3.f/40.f)*hi32(ksp_[0][j]) + (9.f/40.f)*kd_[2*j+1]); \
        by_[j] = pku(ya, yb); }

#define DOP2(x_, ksp_, by_, kd_) \
    _Pragma("unroll") for (int j = 0; j < 4; ++j) { \
        ksp_[2][j] = pku(kd_[2*j], kd_[2*j+1]); \
        float ya = x_[2*j]   + dt*((44.f/45.f)*lo32(ksp_[0][j]) - (56.f/15.f)*lo32(ksp_[1][j]) + (32.f/9.f)*kd_[2*j]); \
        float yb = x_[2*j+1] + dt*((44.f/45.f)*hi32(ksp_[0][j]) - (56.f/15.f)*hi32(ksp_[1][j]) + (32.f/9.f)*kd_[2*j+1]); \
        by_[j] = pku(ya, yb); }

#define DOP3(x_, ksp_, by_, kd_) \
    _Pragma("unroll") for (int j = 0; j < 4; ++j) { \
        ksp_[3][j] = pku(kd_[2*j], kd_[2*j+1]); \
        float ya = x_[2*j]   + dt*((19372.f/6561.f)*lo32(ksp_[0][j]) - (25360.f/2187.f)*lo32(ksp_[1][j]) \
                                + (64448.f/6561.f)*lo32(ksp_[2][j]) - (212.f/729.f)*kd_[2*j]); \
        float yb = x_[2*j+1] + dt*((19372.f/6561.f)*hi32(ksp_[0][j]) - (25360.f/2187.f)*hi32(ksp_[1][j]) \
                                + (64448.f/6561.f)*hi32(ksp_[2][j]) - (212.f/729.f)*kd_[2*j+1]); \
        by_[j] = pku(ya, yb); }

#define DOP4(x_, ksp_, by_, kd_) \
    _Pragma("unroll") for (int j = 0; j < 4; ++j) { \
        ksp_[4][j] = pku(kd_[2*j], kd_[2*j+1]); \
        float ya = x_[2*j]   + dt*((9017.f/3168.f)*lo32(ksp_[0][j]) - (355.f/33.f)*lo32(ksp_[1][j]) \
                                + (46732.f/5247.f)*lo32(ksp_[2][j]) + (49.f/176.f)*lo32(ksp_[3][j]) \
                                - (5103.f/18656.f)*kd_[2*j]); \
        float yb = x_[2*j+1] + dt*((9017.f/3168.f)*hi32(ksp_[0][j]) - (355.f/33.f)*hi32(ksp_[1][j]) \
                                + (46732.f/5247.f)*hi32(ksp_[2][j]) + (49.f/176.f)*hi32(ksp_[3][j]) \
                                - (5103.f/18656.f)*kd_[2*j+1]); \
        by_[j] = pku(ya, yb); }

#define DOP5(x_, ksp_, by_, kd_) \
    _Pragma("unroll") for (int j = 0; j < 4; ++j) { \
        float xa = x_[2*j]   + dt*((35.f/384.f)*lo32(ksp_[0][j]) + (500.f/1113.f)*lo32(ksp_[2][j]) \
                                + (125.f/192.f)*lo32(ksp_[3][j]) - (2187.f/6784.f)*lo32(ksp_[4][j]) \
                                + (11.f/84.f)*kd_[2*j]); \
        float xb = x_[2*j+1] + dt*((35.f/384.f)*hi32(ksp_[0][j]) + (500.f/1113.f)*hi32(ksp_[2][j]) \
                                + (125.f/192.f)*hi32(ksp_[3][j]) - (2187.f/6784.f)*hi32(ksp_[4][j]) \
                                + (11.f/84.f)*kd_[2*j+1]); \
        x_[2*j] = xa; x_[2*j+1] = xb; \
        by_[j] = pku(xa, xb); }

__global__ __launch_bounds__(BT)
__attribute__((amdgpu_waves_per_eu(2, 2)))
void ffjord_mfma(
    const float* __restrict__ x_in,
    const float* __restrict__ W1, const float* __restrict__ b1,
    const float* __restrict__ W2, const float* __restrict__ b2,
    const float* __restrict__ W3, const float* __restrict__ b3,
    float* __restrict__ out)
{
    __shared__ SMem sm;

    const int tid  = threadIdx.x;
    const int lane = tid & 63;
    const int mrow = lane & 15;      // my sample within the wave tile
    const int quad = lane >> 4;      // k/feature quad
    const int wid  = tid >> 6;
    // Two samples per thread: A and B tiles are independent 16-sample MFMA
    // B-fragments sharing every weight fragment / C-init.
    const int sidxA = blockIdx.x * 128 + wid * 32 + mrow;
    const int sidxB = sidxA + 16;

    float xA[8], xB[8];
    uint  kspA[5][4], kspB[5][4];
    uint  byA[4], byB[4];

    #pragma unroll
    for (int nt = 0; nt < 2; ++nt) {
        f32x4 va = *(const f32x4*)(x_in + (size_t)sidxA*D + nt*16 + quad*4);
        f32x4 vb = *(const f32x4*)(x_in + (size_t)sidxB*D + nt*16 + quad*4);
        #pragma unroll
        for (int r = 0; r < 4; ++r) { xA[nt*4 + r] = va[r]; xB[nt*4 + r] = vb[r]; }
    }

    const float dt = 0.125f;

    for (int bij = 0; bij < NB; ++bij) {
        const float* W1b = W1 + (size_t)bij * 2*D*H;
        const float* b1b = b1 + bij*H;
        const float* W2b = W2 + (size_t)bij * H*H;
        const float* b2b = b2 + bij*H;
        const float* W3b = W3 + (size_t)bij * H*D;
        const float* b3b = b3 + bij*D;

        __syncthreads();  // prior bijector done reading weights
        // ---- stage weights: fragment-order, k-permuted, f16, tanh-prescaled ----
        #pragma unroll 1
        for (int g = tid; g < 8*64; g += BT) {               // W1f (x TSCL)
            int nt = g >> 6, ln = g & 63, q = (ln >> 4) & 3, mr = ln & 15;
            f16 tmp[8];
            #pragma unroll
            for (int j = 0; j < 8; ++j) {
                int feat = ((j >> 2) << 4) + q*4 + (j & 3);  // phi1
                tmp[j] = (f16)(W1b[(size_t)(D + feat)*H + nt*16 + mr] * TSCL);
            }
            *(f16x8*)&sm.W1f[(size_t)g * 8] = *(f16x8*)tmp;
        }
        #pragma unroll 1
        for (int g = tid; g < 8*4*64; g += BT) {             // W2f (x TSCL)
            int nt = g >> 8, kt = (g >> 6) & 3, ln = g & 63, q = (ln >> 4) & 3, mr = ln & 15;
            f16 tmp[8];
            #pragma unroll
            for (int j = 0; j < 8; ++j) {
                int feat = (2*kt + (j >> 2))*16 + q*4 + (j & 3);  // phi
                tmp[j] = (f16)(W2b[(size_t)feat*H + nt*16 + mr] * TSCL);
            }
            *(f16x8*)&sm.W2f[(size_t)g * 8] = *(f16x8*)tmp;
        }
        #pragma unroll 1
        for (int g = tid; g < 2*4*64; g += BT) {             // W3f (unscaled)
            int nt = g >> 8, kt = (g >> 6) & 3, ln = g & 63, q = (ln >> 4) & 3, mr = ln & 15;
            f16 tmp[8];
            #pragma unroll
            for (int j = 0; j < 8; ++j) {
                int feat = (2*kt + (j >> 2))*16 + q*4 + (j & 3);  // phi
                tmp[j] = (f16)W3b[(size_t)feat*D + nt*16 + mr];
            }
            *(f16x8*)&sm.W3f[(size_t)g * 8] = *(f16x8*)tmp;
        }
        #pragma unroll 1
        for (int n = tid; n < H; n += BT) {                  // biases + t-fold sums (x TSCL)
            float s = 0.f;
            for (int i = 0; i < D; ++i) s += W1b[(size_t)i*H + n];
            sm.S1[n] = s * TSCL; sm.B1[n] = b1b[n] * TSCL; sm.B2[n] = b2b[n] * TSCL;
        }
        if (tid < D) sm.B3[tid] = b3b[tid];
        __syncthreads();

        // y := x  (packed)
        #pragma unroll
        for (int p = 0; p < 4; ++p) {
            byA[p] = pku(xA[2*p], xA[2*p + 1]);
            byB[p] = pku(xB[2*p], xB[2*p + 1]);
        }

        for (int step = 0; step < NSTEPS; ++step) {
            const float t0 = step * dt;
            #pragma unroll 1
            for (int s = 0; s < 6; ++s) {
                const float te = t0 + dt * CC[s];

                // ======== EVAL: two samples share every weight fragment ========
                // layer 1 (K=32): C init = (b1 + te*S1)*TSCL. Output built
                // DIRECTLY as the 4 L2 B-fragments (frag ktg = L1 nt 2ktg,2ktg+1).
                f16x8 fA1[4], fB1[4];
                {
                    union { f16x8 v; uint u[4]; } ba, bb;
                    ba.u[0] = byA[0]; ba.u[1] = byA[1]; ba.u[2] = byA[2]; ba.u[3] = byA[3];
                    bb.u[0] = byB[0]; bb.u[1] = byB[1]; bb.u[2] = byB[2]; bb.u[3] = byB[3];
                    #pragma unroll
                    for (int ktg = 0; ktg < 4; ++ktg) {
                        uint da[4], db[4];
                        #pragma unroll
                        for (int h = 0; h < 2; ++h) {
                            const int nt = ktg*2 + h;
                            f16x8 wf = *(const f16x8*)&sm.W1f[(nt*64 + lane)*8];
                            f32x4 bv = *(const f32x4*)&sm.B1[nt*16 + quad*4];
                            f32x4 sv = *(const f32x4*)&sm.S1[nt*16 + quad*4];
                            f32x4 ci;
                            #pragma unroll
                            for (int r = 0; r < 4; ++r) ci[r] = fmaf(te, sv[r], bv[r]);
                            f32x4 accA = __builtin_amdgcn_mfma_f32_16x16x32_f16(wf, ba.v, ci, 0, 0, 0);
                            f32x4 accB = __builtin_amdgcn_mfma_f32_16x16x32_f16(wf, bb.v, ci, 0, 0, 0);
                            da[h*2+0] = tanh_pk(accA[0], accA[1]);
                            da[h*2+1] = tanh_pk(accA[2], accA[3]);
                            db[h*2+0] = tanh_pk(accB[0], accB[1]);
                            db[h*2+1] = tanh_pk(accB[2], accB[3]);
                        }
                        uintx4 ua = {da[0], da[1], da[2], da[3]};
                        uintx4 ub = {db[0], db[1], db[2], db[3]};
                        fA1[ktg] = __builtin_bit_cast(f16x8, ua);
                        fB1[ktg] = __builtin_bit_cast(f16x8, ub);
                    }
                }
                // layer 2 (K=128) with layer 3 FUSED: each completed ph2
                // fragment (per ktg) feeds its 4 L3 MFMAs immediately and dies.
                float kdA[8], kdB[8];
                {
                    f32x4 a3A[2], a3B[2];
                    #pragma unroll
                    for (int n3 = 0; n3 < 2; ++n3) {
                        f32x4 c = *(const f32x4*)&sm.B3[n3*16 + quad*4];
                        a3A[n3] = c; a3B[n3] = c;
                    }
                    #pragma unroll 1
                    for (int ktg = 0; ktg < 4; ++ktg) {
                        uint da[4], db[4];
                        #pragma unroll
                        for (int h = 0; h < 2; ++h) {
                            const int nt = ktg*2 + h;
                            f32x4 c0 = *(const f32x4*)&sm.B2[nt*16 + quad*4];
                            f32x4 accA = c0, accB = c0;
                            #pragma unroll
                            for (int kt2 = 0; kt2 < 4; ++kt2) {
                                f16x8 wf = *(const f16x8*)&sm.W2f[((nt*4 + kt2)*64 + lane)*8];
                                accA = __builtin_amdgcn_mfma_f32_16x16x32_f16(wf, fA1[kt2], accA, 0, 0, 0);
                                accB = __builtin_amdgcn_mfma_f32_16x16x32_f16(wf, fB1[kt2], accB, 0, 0, 0);
                            }
                            da[h*2+0] = tanh_pk(accA[0], accA[1]);
                            da[h*2+1] = tanh_pk(accA[2], accA[3]);
                            db[h*2+0] = tanh_pk(accB[0], accB[1]);
                            db[h*2+1] = tanh_pk(accB[2], accB[3]);
                        }
                        uintx4 ua = {da[0], da[1], da[2], da[3]};
                        uintx4 ub = {db[0], db[1], db[2], db[3]};
                        f16x8 fra = __builtin_bit_cast(f16x8, ua);
                        f16x8 frb = __builtin_bit_cast(f16x8, ub);
                        #pragma unroll
                        for (int n3 = 0; n3 < 2; ++n3) {
                            f16x8 wf3 = *(const f16x8*)&sm.W3f[((n3*4 + ktg)*64 + lane)*8];
                            a3A[n3] = __builtin_amdgcn_mfma_f32_16x16x32_f16(wf3, fra, a3A[n3], 0, 0, 0);
                            a3B[n3] = __builtin_amdgcn_mfma_f32_16x16x32_f16(wf3, frb, a3B[n3], 0, 0, 0);
                        }
                    }
                    #pragma unroll
                    for (int n3 = 0; n3 < 2; ++n3)
                        #pragma unroll
                        for (int r = 0; r < 4; ++r) {
                            kdA[n3*4 + r] = a3A[n3][r];
                            kdB[n3*4 + r] = a3B[n3][r];
                        }
                }

                // ===== DOPRI combine (both samples) =====
                switch (s) {
                case 0:  DOP0(xA, kspA, byA, kdA) DOP0(xB, kspB, byB, kdB) break;
                case 1:  DOP1(xA, kspA, byA, kdA) DOP1(xB, kspB, byB, kdB) break;
                case 2:  DOP2(xA, kspA, byA, kdA) DOP2(xB, kspB, byB, kdB) break;
                case 3:  DOP3(xA, kspA, byA, kdA) DOP3(xB, kspB, byB, kdB) break;
                case 4:  DOP4(xA, kspA, byA, kdA) DOP4(xB, kspB, byB, kdB) break;
                default: DOP5(xA, kspA, byA, kdA) DOP5(xB, kspB, byB, kdB) break;
                }
            } // stages
        } // steps
    } // bijectors

    #pragma unroll
    for (int nt = 0; nt < 2; ++nt) {
        f32x4 va, vb;
        #pragma unroll
        for (int r = 0; r < 4; ++r) { va[r] = xA[nt*4 + r]; vb[r] = xB[nt*4 + r]; }
        *(f32x4*)(out + (size_t)sidxA*D + nt*16 + quad*4) = va;
        *(f32x4*)(out + (size_t)sidxB*D + nt*16 + quad*4) = vb;
    }
}

extern "C" void kernel_launch(void* const* d_in, const int* in_sizes, int n_in,
                              void* d_out, int out_size, void* d_ws, size_t ws_size,
                              hipStream_t stream) {
    (void)d_ws; (void)ws_size; (void)n_in; (void)out_size;
    const float* x  = (const float*)d_in[0];
    const float* W1 = (const float*)d_in[1];
    const float* b1 = (const float*)d_in[2];
    const float* W2 = (const float*)d_in[3];
    const float* b2 = (const float*)d_in[4];
    const float* W3 = (const float*)d_in[5];
    const float* b3 = (const float*)d_in[6];
    float* out = (float*)d_out;

    const int n = in_sizes[0] / D;          // 65536 samples
    const int grid = n / 128;               // 512 blocks (128 samples each), exact
    ffjord_mfma<<<grid, BT, 0, stream>>>(x, W1, b1, W2, b2, W3, b3, out);
}